// Round 1
// baseline (758.626 us; speedup 1.0000x reference)
//
#include <hip/hip_runtime.h>
#include <hip/hip_bf16.h>

// Problem constants: B=4, S=2048, D=1024, H=16, KV=4, HD=64, GROUPS=4
#define S_LEN 2048
#define DMODEL 1024
#define NQH 16
#define HDIM 64

typedef __attribute__((ext_vector_type(8))) short bf16x8;
typedef __attribute__((ext_vector_type(4))) float f32x4;

__device__ inline unsigned short f2bf(float x) {
    unsigned int u = __float_as_uint(x);
    u += 0x7fffu + ((u >> 16) & 1u);          // round-to-nearest-even
    return (unsigned short)(u >> 16);
}
__device__ inline float bf2f(unsigned short b) {
    return __uint_as_float(((unsigned int)b) << 16);
}

// ---------------------------------------------------------------------------
// GEMM: C[M,N] = A[M,K] @ B[K,N].
//   TA=float  -> A is fp32, split into hi/lo bf16 (2 MFMAs) for ~fp32-grade A
//   TA=ushort -> A is bf16 already (no split)
//   OUT_BF16  -> C stored as bf16, else fp32
// Tile: 64x64 per block, 256 threads = 4 waves, each wave owns 16 rows.
// BK=32 staged in LDS; B staged transposed so B-frag is a contiguous b128.
// ---------------------------------------------------------------------------
template <typename TA, bool OUT_BF16>
__global__ __launch_bounds__(256)
void gemm_kernel(const TA* __restrict__ A, const float* __restrict__ B,
                 void* __restrict__ Cout, int M, int N, int K) {
    constexpr bool SPLIT = (sizeof(TA) == 4);
    __shared__ __attribute__((aligned(16))) unsigned short As_hi[64][40];
    __shared__ __attribute__((aligned(16))) unsigned short As_lo[SPLIT ? 64 : 1][40];
    __shared__ __attribute__((aligned(16))) unsigned short Bt[64][40];   // Bt[n][k]

    const int tid = threadIdx.x;
    const int w = tid >> 6, lane = tid & 63;
    const int quad = lane >> 4, l15 = lane & 15;
    const long row0 = (long)blockIdx.x * 64;
    const long col0 = (long)blockIdx.y * 64;

    f32x4 acc[4];
#pragma unroll
    for (int nb = 0; nb < 4; ++nb) acc[nb] = (f32x4){0.f, 0.f, 0.f, 0.f};

    for (int kt = 0; kt < K; kt += 32) {
        __syncthreads();
        // Stage A tile (64 x 32)
#pragma unroll
        for (int i = 0; i < 2; ++i) {
            int idx = tid + i * 256;          // 0..511
            int r = idx >> 3, c4 = idx & 7;   // row, float4-col
            if constexpr (SPLIT) {
                const float4 av = *(const float4*)((const float*)A + (row0 + r) * (long)K + kt + c4 * 4);
                float vs[4] = {av.x, av.y, av.z, av.w};
#pragma unroll
                for (int e = 0; e < 4; ++e) {
                    unsigned short hi = f2bf(vs[e]);
                    As_hi[r][c4 * 4 + e] = hi;
                    As_lo[r][c4 * 4 + e] = f2bf(vs[e] - bf2f(hi));
                }
            } else {
                const ushort4 av = *(const ushort4*)((const unsigned short*)A + (row0 + r) * (long)K + kt + c4 * 4);
                As_hi[r][c4 * 4 + 0] = av.x;
                As_hi[r][c4 * 4 + 1] = av.y;
                As_hi[r][c4 * 4 + 2] = av.z;
                As_hi[r][c4 * 4 + 3] = av.w;
            }
        }
        // Stage B tile (32 x 64), transposed into Bt[n][k]
#pragma unroll
        for (int i = 0; i < 2; ++i) {
            int idx = tid + i * 256;           // 0..511
            int r = idx >> 4, c4 = idx & 15;   // k-row, float4-col
            const float4 bv = *(const float4*)(B + (long)(kt + r) * N + col0 + c4 * 4);
            Bt[c4 * 4 + 0][r] = f2bf(bv.x);
            Bt[c4 * 4 + 1][r] = f2bf(bv.y);
            Bt[c4 * 4 + 2][r] = f2bf(bv.z);
            Bt[c4 * 4 + 3][r] = f2bf(bv.w);
        }
        __syncthreads();

        bf16x8 ah = *(const bf16x8*)&As_hi[w * 16 + l15][quad * 8];
        bf16x8 al;
        if constexpr (SPLIT) al = *(const bf16x8*)&As_lo[w * 16 + l15][quad * 8];
#pragma unroll
        for (int nb = 0; nb < 4; ++nb) {
            bf16x8 bf = *(const bf16x8*)&Bt[nb * 16 + l15][quad * 8];
            if constexpr (SPLIT)
                acc[nb] = __builtin_amdgcn_mfma_f32_16x16x32_bf16(al, bf, acc[nb], 0, 0, 0);
            acc[nb] = __builtin_amdgcn_mfma_f32_16x16x32_bf16(ah, bf, acc[nb], 0, 0, 0);
        }
    }

    // Epilogue: C/D layout col=lane&15, row=quad*4+reg (m89/m91-verified)
#pragma unroll
    for (int nb = 0; nb < 4; ++nb)
#pragma unroll
        for (int r = 0; r < 4; ++r) {
            long row = row0 + w * 16 + quad * 4 + r;
            long col = col0 + nb * 16 + l15;
            if constexpr (OUT_BF16)
                ((unsigned short*)Cout)[row * N + col] = f2bf(acc[nb][r]);
            else
                ((float*)Cout)[row * N + col] = acc[nb][r];
        }
}

// ---------------------------------------------------------------------------
// Flash attention with ALiBi (non-causal), GQA group = 4.
// Grid: (S/64, H, B). Block 256 = 4 waves; wave w owns 16 query rows.
// Q/K frags loaded straight from global (bf16, L2-resident).
// V transposed into LDS; P round-trips LDS (C-layout -> A-layout).
// ---------------------------------------------------------------------------
template <bool OBF16>
__global__ __launch_bounds__(256)
void attn_kernel(const unsigned short* __restrict__ Qb,
                 const unsigned short* __restrict__ Kb,
                 const unsigned short* __restrict__ Vb,
                 void* __restrict__ O) {
    __shared__ __attribute__((aligned(16))) unsigned short Vt[64][72];      // V^T[d][k]
    __shared__ __attribute__((aligned(16))) unsigned short Pl[4][16][72];   // per-wave P

    const int tid = threadIdx.x;
    const int w = tid >> 6, lane = tid & 63;
    const int quad = lane >> 4, l15 = lane & 15;
    const int qt = blockIdx.x, h = blockIdx.y, b = blockIdx.z;
    const int kvh = h >> 2;                       // GROUPS = 4
    const float scale = 0.125f;                   // 64^-0.5
    const float slope = exp2f(-0.5f * (float)(h + 1));   // alibi slope for head h
    const long qrowbase = (long)b * S_LEN + (long)qt * 64;

    // Q fragments (A-operand): A[m=lane&15][k=quad*8+j], two 32-wide k-chunks
    bf16x8 qfrag[2];
    {
        const unsigned short* qp = Qb + (qrowbase + w * 16 + l15) * DMODEL + h * HDIM + quad * 8;
        qfrag[0] = *(const bf16x8*)qp;
        qfrag[1] = *(const bf16x8*)(qp + 32);
    }

    f32x4 oacc[4];
    float m_i[4], l_i[4];
#pragma unroll
    for (int nb = 0; nb < 4; ++nb) oacc[nb] = (f32x4){0.f, 0.f, 0.f, 0.f};
#pragma unroll
    for (int r = 0; r < 4; ++r) { m_i[r] = -1e30f; l_i[r] = 0.f; }

    for (int kt = 0; kt < S_LEN / 64; ++kt) {
        __syncthreads();   // protect Vt from previous iteration's readers
        // Stage V^T: 64 keys x 64 dims, vectorized global read, scalar LDS scatter
#pragma unroll
        for (int i = 0; i < 2; ++i) {
            int idx = tid + i * 256;          // 0..511
            int k = idx >> 3, d8 = idx & 7;
            const unsigned short* vp = Vb + ((long)b * S_LEN + kt * 64 + k) * 256 + kvh * HDIM + d8 * 8;
            bf16x8 vv = *(const bf16x8*)vp;
#pragma unroll
            for (int e = 0; e < 8; ++e) Vt[d8 * 8 + e][k] = (unsigned short)vv[e];
        }
        __syncthreads();

        // Scores: S = Q @ K^T ; B-frag = K[key=lane&15][d=quad*8+j] (contiguous)
        f32x4 s[4];
        const long krow0 = (long)b * S_LEN + kt * 64;
#pragma unroll
        for (int kb = 0; kb < 4; ++kb) {
            const unsigned short* kp = Kb + (krow0 + kb * 16 + l15) * 256 + kvh * HDIM + quad * 8;
            bf16x8 k0 = *(const bf16x8*)kp;
            bf16x8 k1 = *(const bf16x8*)(kp + 32);
            f32x4 z = (f32x4){0.f, 0.f, 0.f, 0.f};
            z = __builtin_amdgcn_mfma_f32_16x16x32_bf16(qfrag[0], k0, z, 0, 0, 0);
            z = __builtin_amdgcn_mfma_f32_16x16x32_bf16(qfrag[1], k1, z, 0, 0, 0);
            s[kb] = z;
        }

        // scale + alibi; C layout: col(key)=l15, row(q)=quad*4+r
        const int qpos0 = qt * 64 + w * 16 + quad * 4;
        const int kpos0 = kt * 64 + l15;
#pragma unroll
        for (int kb = 0; kb < 4; ++kb) {
            const int key = kpos0 + kb * 16;
#pragma unroll
            for (int r = 0; r < 4; ++r)
                s[kb][r] = s[kb][r] * scale + slope * (float)(key - (qpos0 + r));
        }

        // online softmax (row reduce across the 16 lanes of the quad)
        float alpha[4];
#pragma unroll
        for (int r = 0; r < 4; ++r) {
            float m = fmaxf(fmaxf(s[0][r], s[1][r]), fmaxf(s[2][r], s[3][r]));
#pragma unroll
            for (int off = 1; off < 16; off <<= 1)
                m = fmaxf(m, __shfl_xor(m, off, 64));
            float mn = fmaxf(m_i[r], m);
            alpha[r] = __expf(m_i[r] - mn);
            m_i[r] = mn;
            float ps = 0.f;
#pragma unroll
            for (int kb = 0; kb < 4; ++kb) {
                float p = __expf(s[kb][r] - mn);
                s[kb][r] = p;
                ps += p;
            }
#pragma unroll
            for (int off = 1; off < 16; off <<= 1)
                ps += __shfl_xor(ps, off, 64);
            l_i[r] = l_i[r] * alpha[r] + ps;
        }
#pragma unroll
        for (int nb = 0; nb < 4; ++nb)
#pragma unroll
            for (int r = 0; r < 4; ++r) oacc[nb][r] *= alpha[r];

        // P: C-layout -> LDS -> A-layout
#pragma unroll
        for (int kb = 0; kb < 4; ++kb)
#pragma unroll
            for (int r = 0; r < 4; ++r)
                Pl[w][quad * 4 + r][kb * 16 + l15] = f2bf(s[kb][r]);
        __syncthreads();

        // O += P @ V ; B-frag = Vt[n=nb*16+l15][k=ch*32+quad*8+j] (contiguous)
#pragma unroll
        for (int ch = 0; ch < 2; ++ch) {
            bf16x8 pf = *(const bf16x8*)&Pl[w][l15][ch * 32 + quad * 8];
#pragma unroll
            for (int nb = 0; nb < 4; ++nb) {
                bf16x8 vf = *(const bf16x8*)&Vt[nb * 16 + l15][ch * 32 + quad * 8];
                oacc[nb] = __builtin_amdgcn_mfma_f32_16x16x32_bf16(pf, vf, oacc[nb], 0, 0, 0);
            }
        }
    }

    // epilogue: O[q, h*64 + d] = acc / l
#pragma unroll
    for (int nb = 0; nb < 4; ++nb)
#pragma unroll
        for (int r = 0; r < 4; ++r) {
            long row = qrowbase + w * 16 + quad * 4 + r;
            long col = h * HDIM + nb * 16 + l15;
            float v = oacc[nb][r] / l_i[r];
            if constexpr (OBF16)
                ((unsigned short*)O)[row * DMODEL + col] = f2bf(v);
            else
                ((float*)O)[row * DMODEL + col] = v;
        }
}

// ---------------------------------------------------------------------------
extern "C" void kernel_launch(void* const* d_in, const int* in_sizes, int n_in,
                              void* d_out, int out_size, void* d_ws, size_t ws_size,
                              hipStream_t stream) {
    const float* x  = (const float*)d_in[0];
    const float* Wq = (const float*)d_in[1];
    const float* Wk = (const float*)d_in[2];
    const float* Wv = (const float*)d_in[3];
    const float* Wo = (const float*)d_in[4];
    float* out = (float*)d_out;
    char* ws = (char*)d_ws;
    const int M = 4 * S_LEN;   // 8192

    // workspace layout (bytes): Q bf16 16MB | K bf16 4MB | V bf16 4MB | O 32MB(f32) or 16MB(bf16)
    unsigned short* Qb = (unsigned short*)ws;
    unsigned short* Kb = (unsigned short*)(ws + (size_t)16 * 1024 * 1024);
    unsigned short* Vb = (unsigned short*)(ws + (size_t)20 * 1024 * 1024);
    void* Ob = (void*)(ws + (size_t)24 * 1024 * 1024);

    dim3 blk(256);
    gemm_kernel<float, true><<<dim3(128, 16), blk, 0, stream>>>(x, Wq, Qb, M, 1024, 1024);
    gemm_kernel<float, true><<<dim3(128, 4),  blk, 0, stream>>>(x, Wk, Kb, M, 256, 1024);
    gemm_kernel<float, true><<<dim3(128, 4),  blk, 0, stream>>>(x, Wv, Vb, M, 256, 1024);

    const bool bigws = ws_size >= (size_t)56 * 1024 * 1024;
    if (bigws) {
        // O kept fp32 -> split-A output projection (better precision)
        attn_kernel<false><<<dim3(S_LEN / 64, NQH, 4), blk, 0, stream>>>(Qb, Kb, Vb, Ob);
        gemm_kernel<float, false><<<dim3(128, 16), blk, 0, stream>>>((const float*)Ob, Wo, out, M, 1024, 1024);
    } else {
        attn_kernel<true><<<dim3(S_LEN / 64, NQH, 4), blk, 0, stream>>>(Qb, Kb, Vb, Ob);
        gemm_kernel<unsigned short, false><<<dim3(128, 16), blk, 0, stream>>>((const unsigned short*)Ob, Wo, out, M, 1024, 1024);
    }
}

// Round 2
// 335.086 us; speedup vs baseline: 2.2640x; 2.2640x over previous
//
#include <hip/hip_runtime.h>

typedef unsigned short u16;
typedef unsigned int u32;
typedef __attribute__((ext_vector_type(8))) short bf16x8;
typedef __attribute__((ext_vector_type(4))) float f32x4;

#define S_LEN 2048
#define DM 1024
#define QKVW 1536

__device__ __forceinline__ u16 f2bf(float x) {
    u32 u = __float_as_uint(x);
    u += 0x7fffu + ((u >> 16) & 1u);
    return (u16)(u >> 16);
}
__device__ __forceinline__ float bf2f(u16 b) { return __uint_as_float(((u32)b) << 16); }

__device__ __forceinline__ void g2l16(const void* g, void* l) {
    __builtin_amdgcn_global_load_lds((const __attribute__((address_space(1))) u32*)g,
                                     (__attribute__((address_space(3))) u32*)l, 16, 0, 0);
}

// ---------------------------------------------------------------------------
// x (f32) -> xh, xl bf16 split
__global__ void convert_x(const float* __restrict__ x, u16* __restrict__ xh,
                          u16* __restrict__ xl, int n4) {
    int i = blockIdx.x * blockDim.x + threadIdx.x;
    if (i >= n4) return;
    float4 v = ((const float4*)x)[i];
    float vs[4] = {v.x, v.y, v.z, v.w};
    ushort4 h, l;
    u16 hh[4], ll[4];
#pragma unroll
    for (int e = 0; e < 4; ++e) {
        hh[e] = f2bf(vs[e]);
        ll[e] = f2bf(vs[e] - bf2f(hh[e]));
    }
    h = make_ushort4(hh[0], hh[1], hh[2], hh[3]);
    ((ushort4*)xh)[i] = h;
    if (xl) {
        l = make_ushort4(ll[0], ll[1], ll[2], ll[3]);
        ((ushort4*)xl)[i] = l;
    }
}

// W f32 [R][C] -> Wt bf16 [C][R]  (dst pre-offset; dst row stride = R)
__global__ void transpose_f2b(const float* __restrict__ src, u16* __restrict__ dst,
                              int R, int C) {
    __shared__ float t[32][33];
    int c0 = blockIdx.x * 32, r0 = blockIdx.y * 32;
    int tx = threadIdx.x, ty = threadIdx.y;
#pragma unroll
    for (int i = 0; i < 4; ++i)
        t[ty + 8 * i][tx] = src[(long)(r0 + ty + 8 * i) * C + c0 + tx];
    __syncthreads();
#pragma unroll
    for (int i = 0; i < 4; ++i)
        dst[(long)(c0 + ty + 8 * i) * R + r0 + tx] = f2bf(t[tx][ty + 8 * i]);
}

// V cols of QKV (bf16) -> Vt[(b*4+kv)*64+d][s]
__global__ void transpose_v(const u16* __restrict__ qkv, u16* __restrict__ vt) {
    __shared__ u16 t[32][33];
    int b = blockIdx.z;
    int s0 = blockIdx.x * 32, c0 = blockIdx.y * 32;
    int tx = threadIdx.x, ty = threadIdx.y;
#pragma unroll
    for (int i = 0; i < 4; ++i)
        t[ty + 8 * i][tx] = qkv[((long)(b * S_LEN + s0 + ty + 8 * i)) * QKVW + 1280 + c0 + tx];
    __syncthreads();
#pragma unroll
    for (int i = 0; i < 4; ++i)
        vt[((long)(b * 256 + c0 + ty + 8 * i)) * S_LEN + s0 + tx] = t[tx][ty + 8 * i];
}

// ---------------------------------------------------------------------------
// m97-style GEMM: C[M,N] = A @ B,  A bf16 (optionally hi+lo split), Bt = B^T bf16 [N][K].
// 128x128 tile, BK=32, global_load_lds(16B) staging, XOR chunk swizzle (row&3).
template <bool SPLIT, bool OUT_BF16>
__global__ __launch_bounds__(256, 3)
void gemm_bt(const u16* __restrict__ Ah, const u16* __restrict__ Al,
             const u16* __restrict__ Bt, void* __restrict__ C, int N, int K) {
    __shared__ __attribute__((aligned(16))) u16 sA[(SPLIT ? 2 : 1)][128 * 32];
    __shared__ __attribute__((aligned(16))) u16 sB[128 * 32];
    const int tid = threadIdx.x, w = tid >> 6, lane = tid & 63;
    const int quad = lane >> 4, l15 = lane & 15;
    const int wm = w & 1, wn = w >> 1;
    const long row0 = (long)blockIdx.x * 128, col0 = (long)blockIdx.y * 128;
    const int NB = SPLIT ? 3 : 2;  // number of LDS buffers

    f32x4 acc[4][4];
#pragma unroll
    for (int mb = 0; mb < 4; ++mb)
#pragma unroll
        for (int nb = 0; nb < 4; ++nb) acc[mb][nb] = (f32x4){0.f, 0.f, 0.f, 0.f};

    const int r = lane >> 2;                // row within 16-row segment
    const int cch = (lane & 3) ^ (r & 3);   // swizzled 16B chunk

    for (int kt = 0; kt < K; kt += 32) {
        __syncthreads();
#pragma unroll
        for (int i = 0; i < 2 * (SPLIT ? 3 : 2); ++i) {
            int gid = w + 4 * i;            // 0 .. NB*8-1
            int buf = gid >> 3, seg = gid & 7;
            const u16* src = (buf == NB - 1) ? Bt : (buf == 0 ? Ah : Al);
            long base0 = (buf == NB - 1) ? col0 : row0;
            const u16* g = src + (base0 + seg * 16 + r) * (long)K + kt + cch * 8;
            u16* dst = ((buf == NB - 1) ? sB : sA[buf]) + seg * 512;
            g2l16(g, dst);
        }
        __syncthreads();

        bf16x8 bfr[4];
#pragma unroll
        for (int nb = 0; nb < 4; ++nb) {
            int rr = wn * 64 + nb * 16 + l15;
            bfr[nb] = *(const bf16x8*)(sB + rr * 32 + ((quad ^ (l15 & 3)) * 8));
        }
#pragma unroll
        for (int mb = 0; mb < 4; ++mb) {
            int rr = wm * 64 + mb * 16 + l15;
            int off = rr * 32 + ((quad ^ (l15 & 3)) * 8);
            bf16x8 ah = *(const bf16x8*)(sA[0] + off);
            bf16x8 al;
            if constexpr (SPLIT) al = *(const bf16x8*)(sA[SPLIT ? 1 : 0] + off);
#pragma unroll
            for (int nb = 0; nb < 4; ++nb) {
                if constexpr (SPLIT)
                    acc[mb][nb] = __builtin_amdgcn_mfma_f32_16x16x32_bf16(al, bfr[nb], acc[mb][nb], 0, 0, 0);
                acc[mb][nb] = __builtin_amdgcn_mfma_f32_16x16x32_bf16(ah, bfr[nb], acc[mb][nb], 0, 0, 0);
            }
        }
    }
#pragma unroll
    for (int mb = 0; mb < 4; ++mb)
#pragma unroll
        for (int nb = 0; nb < 4; ++nb)
#pragma unroll
            for (int rr = 0; rr < 4; ++rr) {
                long row = row0 + wm * 64 + mb * 16 + quad * 4 + rr;
                long col = col0 + wn * 64 + nb * 16 + l15;
                if constexpr (OUT_BF16)
                    ((u16*)C)[row * N + col] = f2bf(acc[mb][nb][rr]);
                else
                    ((float*)C)[row * N + col] = acc[mb][nb][rr];
            }
}

// ---------------------------------------------------------------------------
// Flash attention, ALiBi static-max (no online max, no shuffles in loop).
// Block: 256 thr = 4 waves x 32 q-rows = 128 q-rows. K staged in LDS (swizzled),
// V^T direct from global, P via per-wave LDS round-trip.
template <bool WLO>
__global__ __launch_bounds__(256, 4)
void attn(const u16* __restrict__ qkv, const u16* __restrict__ vt,
          u16* __restrict__ Oh, u16* __restrict__ Ol) {
    __shared__ __attribute__((aligned(16))) u16 sK[64 * 64];       // rows of 128B, slot-swizzled
    __shared__ __attribute__((aligned(16))) u16 sP[4][2][16][72];  // per-wave P
    const int tid = threadIdx.x, w = tid >> 6, lane = tid & 63;
    const int quad = lane >> 4, l15 = lane & 15;
    const int qt = blockIdx.x, h = blockIdx.y, b = blockIdx.z;
    const int kvh = h >> 2;
    const float c1 = 0.125f * 1.44269504f;
    const float c2 = __builtin_amdgcn_exp2f(-0.5f * (float)(h + 1)) * 1.44269504f;
    const float d0 = -8.0f - c2 * 2047.0f;  // query position cancels analytically
    const long qrow0 = (long)b * S_LEN + (long)qt * 128;

    bf16x8 qf[2][2];
#pragma unroll
    for (int mb = 0; mb < 2; ++mb)
#pragma unroll
        for (int ch = 0; ch < 2; ++ch)
            qf[mb][ch] = *(const bf16x8*)(qkv + (qrow0 + w * 32 + mb * 16 + l15) * QKVW +
                                          h * 64 + ch * 32 + quad * 8);

    f32x4 oacc[2][4];
    float lsum[2][4];
#pragma unroll
    for (int mb = 0; mb < 2; ++mb)
#pragma unroll
        for (int nb = 0; nb < 4; ++nb) oacc[mb][nb] = (f32x4){0.f, 0.f, 0.f, 0.f};
#pragma unroll
    for (int mb = 0; mb < 2; ++mb)
#pragma unroll
        for (int rr = 0; rr < 4; ++rr) lsum[mb][rr] = 0.f;

    const int krs = lane >> 3;           // staging row within segment
    const int ksl = (lane & 7) ^ krs;    // swizzled slot

    for (int kt = 0; kt < S_LEN / 64; ++kt) {
        __syncthreads();
#pragma unroll
        for (int i = 0; i < 2; ++i) {
            int seg = w * 2 + i;
            const u16* g = qkv + ((long)(b * S_LEN + kt * 64 + seg * 8 + krs)) * QKVW +
                           1024 + kvh * 64 + ksl * 8;
            g2l16(g, sK + seg * 512);
        }
        __syncthreads();

        // K fragments from swizzled LDS (2-way max -> free)
        bf16x8 kf[4][2];
#pragma unroll
        for (int kb = 0; kb < 4; ++kb)
#pragma unroll
            for (int ch = 0; ch < 2; ++ch) {
                int row = kb * 16 + l15;
                kf[kb][ch] = *(const bf16x8*)(sK + row * 64 + (((ch * 4 + quad) ^ (l15 & 7)) * 8));
            }

        const float kcb = fmaf(c2, (float)(kt * 64 + l15), d0);
#pragma unroll
        for (int mb = 0; mb < 2; ++mb) {
#pragma unroll
            for (int kb = 0; kb < 4; ++kb) {
                f32x4 z = (f32x4){0.f, 0.f, 0.f, 0.f};
                z = __builtin_amdgcn_mfma_f32_16x16x32_bf16(qf[mb][0], kf[kb][0], z, 0, 0, 0);
                z = __builtin_amdgcn_mfma_f32_16x16x32_bf16(qf[mb][1], kf[kb][1], z, 0, 0, 0);
                float kc = fmaf(c2, (float)(16 * kb), kcb);
#pragma unroll
                for (int rr = 0; rr < 4; ++rr) {
                    float t = fmaf(z[rr], c1, kc);
                    float p = __builtin_amdgcn_exp2f(t);
                    u32 u = __float_as_uint(p);
                    lsum[mb][rr] += __uint_as_float(u & 0xffff0000u);  // consistent w/ stored P
                    sP[w][mb][quad * 4 + rr][kb * 16 + l15] = (u16)(u >> 16);
                }
            }
        }
        // PV: V^T direct from global (L1), P from per-wave LDS (in-order DS => safe)
#pragma unroll
        for (int ch = 0; ch < 2; ++ch) {
            bf16x8 vf[4];
#pragma unroll
            for (int nb = 0; nb < 4; ++nb)
                vf[nb] = *(const bf16x8*)(vt + ((long)((b * 4 + kvh) * 64 + nb * 16 + l15)) * S_LEN +
                                          kt * 64 + ch * 32 + quad * 8);
#pragma unroll
            for (int mb = 0; mb < 2; ++mb) {
                bf16x8 pf = *(const bf16x8*)(&sP[w][mb][l15][ch * 32 + quad * 8]);
#pragma unroll
                for (int nb = 0; nb < 4; ++nb)
                    oacc[mb][nb] = __builtin_amdgcn_mfma_f32_16x16x32_bf16(pf, vf[nb], oacc[mb][nb], 0, 0, 0);
            }
        }
    }

    float linv[2][4];
#pragma unroll
    for (int mb = 0; mb < 2; ++mb)
#pragma unroll
        for (int rr = 0; rr < 4; ++rr) {
            float v = lsum[mb][rr];
#pragma unroll
            for (int off = 1; off < 16; off <<= 1) v += __shfl_xor(v, off, 64);
            linv[mb][rr] = 1.0f / v;
        }
#pragma unroll
    for (int mb = 0; mb < 2; ++mb)
#pragma unroll
        for (int nb = 0; nb < 4; ++nb)
#pragma unroll
            for (int rr = 0; rr < 4; ++rr) {
                long row = qrow0 + w * 32 + mb * 16 + quad * 4 + rr;
                long col = h * 64 + nb * 16 + l15;
                float v = oacc[mb][nb][rr] * linv[mb][rr];
                u16 hh = f2bf(v);
                Oh[row * DM + col] = hh;
                if constexpr (WLO) Ol[row * DM + col] = f2bf(v - bf2f(hh));
            }
}

// ---------------------------------------------------------------------------
extern "C" void kernel_launch(void* const* d_in, const int* in_sizes, int n_in,
                              void* d_out, int out_size, void* d_ws, size_t ws_size,
                              hipStream_t stream) {
    const float* x = (const float*)d_in[0];
    const float* Wq = (const float*)d_in[1];
    const float* Wk = (const float*)d_in[2];
    const float* Wv = (const float*)d_in[3];
    const float* Wo = (const float*)d_in[4];
    char* ws = (char*)d_ws;
    const size_t MB = 1 << 20;
    const bool big = ws_size >= 66 * MB;

    u16 *xh, *xl, *Wtq, *Wto, *QKV, *Vt, *Oh, *Ol;
    if (big) {
        xh = (u16*)ws;                  // 16MB
        xl = (u16*)(ws + 16 * MB);      // 16MB
        Wtq = (u16*)(ws + 32 * MB);     // 3MB
        Wto = (u16*)(ws + 35 * MB);     // 2MB
        QKV = (u16*)(ws + 37 * MB);     // 24MB
        Vt = (u16*)(ws + 61 * MB);      // 4MB (total 65MB)
        Oh = xh;                        // x dead after QKV GEMM
        Ol = xl;
    } else {
        xh = (u16*)ws;                  // 16MB
        xl = nullptr;
        Wtq = (u16*)(ws + 16 * MB);
        Wto = (u16*)(ws + 19 * MB);
        QKV = (u16*)(ws + 21 * MB);
        Vt = (u16*)(ws + 45 * MB);      // total 49MB
        Oh = xh;
        Ol = nullptr;
    }

    dim3 t328(32, 8);
    convert_x<<<8192, 256, 0, stream>>>(x, xh, xl, (8192 * 1024) / 4);
    transpose_f2b<<<dim3(32, 32), t328, 0, stream>>>(Wq, Wtq, 1024, 1024);
    transpose_f2b<<<dim3(8, 32), t328, 0, stream>>>(Wk, Wtq + 1024 * 1024, 1024, 256);
    transpose_f2b<<<dim3(8, 32), t328, 0, stream>>>(Wv, Wtq + 1280 * 1024, 1024, 256);
    transpose_f2b<<<dim3(32, 32), t328, 0, stream>>>(Wo, Wto, 1024, 1024);

    if (big)
        gemm_bt<true, true><<<dim3(64, 12), 256, 0, stream>>>(xh, xl, Wtq, QKV, QKVW, 1024);
    else
        gemm_bt<false, true><<<dim3(64, 12), 256, 0, stream>>>(xh, nullptr, Wtq, QKV, QKVW, 1024);

    transpose_v<<<dim3(64, 8, 4), t328, 0, stream>>>(QKV, Vt);

    if (big) {
        attn<true><<<dim3(16, 16, 4), 256, 0, stream>>>(QKV, Vt, Oh, Ol);
        gemm_bt<true, false><<<dim3(64, 8), 256, 0, stream>>>(Oh, Ol, Wto, d_out, 1024, 1024);
    } else {
        attn<false><<<dim3(16, 16, 4), 256, 0, stream>>>(QKV, Vt, Oh, nullptr);
        gemm_bt<false, false><<<dim3(64, 8), 256, 0, stream>>>(Oh, nullptr, Wto, d_out, 1024, 1024);
    }
}